// Round 1
// baseline (341.797 us; speedup 1.0000x reference)
//
#include <hip/hip_runtime.h>

// LIF recurrence: T timesteps, BN independent neurons.
// mem_{t+1} = (0.5*mem_t + syn_t) * (1 - out_t); syn_{t+1} = in[t]; out_t = mem_t > 1.
// Memory-bound: 210 MB read + 210 MB write, floor ~67 us at 6.3 TB/s.

constexpr int T_STEPS = 100;

__global__ __launch_bounds__(256) void lif_kernel(const float4* __restrict__ in,
                                                  float4* __restrict__ out,
                                                  int bn4) {
    const int i = blockIdx.x * blockDim.x + threadIdx.x;
    if (i >= bn4) return;

    float4 mem = make_float4(0.f, 0.f, 0.f, 0.f);
    float4 syn = make_float4(0.f, 0.f, 0.f, 0.f);

    const float4* __restrict__ ip = in + i;
    float4* __restrict__ op = out + i;

#pragma unroll 4
    for (int t = 0; t < T_STEPS; ++t) {
        // Load for step t (becomes syn at t+1) — independent of this step's state math,
        // so the compiler can issue it early and keep several in flight.
        float4 h = ip[(long)t * bn4];

        float4 o;
        o.x = mem.x > 1.0f ? 1.0f : 0.0f;
        o.y = mem.y > 1.0f ? 1.0f : 0.0f;
        o.z = mem.z > 1.0f ? 1.0f : 0.0f;
        o.w = mem.w > 1.0f ? 1.0f : 0.0f;

        // detach_reset: mem zeroed where spiked, else leaky integrate of current syn.
        mem.x = (o.x != 0.0f) ? 0.0f : fmaf(0.5f, mem.x, syn.x);
        mem.y = (o.y != 0.0f) ? 0.0f : fmaf(0.5f, mem.y, syn.y);
        mem.z = (o.z != 0.0f) ? 0.0f : fmaf(0.5f, mem.z, syn.z);
        mem.w = (o.w != 0.0f) ? 0.0f : fmaf(0.5f, mem.w, syn.w);

        syn = h;

        op[(long)t * bn4] = o;
    }
}

extern "C" void kernel_launch(void* const* d_in, const int* in_sizes, int n_in,
                              void* d_out, int out_size, void* d_ws, size_t ws_size,
                              hipStream_t stream) {
    const float* in = (const float*)d_in[0];
    float* out = (float*)d_out;

    const int total = in_sizes[0];          // T * B * N
    const int bn = total / T_STEPS;         // B * N = 524288
    const int bn4 = bn / 4;                 // float4 elements per timestep

    const int block = 256;
    const int grid = (bn4 + block - 1) / block;  // 512 blocks

    lif_kernel<<<grid, block, 0, stream>>>((const float4*)in, (float4*)out, bn4);
}

// Round 2
// 330.907 us; speedup vs baseline: 1.0329x; 1.0329x over previous
//
#include <hip/hip_runtime.h>

// LIF recurrence: T timesteps, BN independent neurons.
// mem_{t+1} = (0.5*mem_t + syn_t) * (1 - out_t); syn_{t+1} = in[t]; out_t = mem_t > 1.
// Memory-bound: 210 MB read + 210 MB write, floor ~67 us at 6.3 TB/s achievable.
//
// Round 1 -> 2 changes:
//  - float2 instead of float4: 262144 threads = 1024 blocks = 4 waves/SIMD (was 2).
//    T-loop is forcibly serial per thread, so TLP is the main latency hider.
//  - Explicit distance-2 prefetch pipeline (hA/hB rotation): two loads always in
//    flight, so the consume point can wait at vmcnt(>0) instead of a full drain.
//  - Full unroll (T=100 known at compile time) so the rotation is register renaming.
//  - Nontemporal load/store: both streams are touch-once, skip cache allocation.

constexpr int T_STEPS = 100;

typedef float v2f __attribute__((ext_vector_type(2)));

__global__ __launch_bounds__(256) void lif_kernel(const v2f* __restrict__ in,
                                                  v2f* __restrict__ out,
                                                  int bn2) {
    const int i = blockIdx.x * blockDim.x + threadIdx.x;
    if (i >= bn2) return;

    const v2f* __restrict__ ip = in + i;
    v2f* __restrict__ op = out + i;

    v2f mem = 0.0f;
    v2f syn = 0.0f;

    // Prime the 2-deep pipeline: h_0 and h_1 in flight.
    v2f hA = __builtin_nontemporal_load(ip);
    v2f hB = __builtin_nontemporal_load(ip + (long)bn2);

#pragma unroll
    for (int t = 0; t < T_STEPS; ++t) {
        // Issue load for t+2 before consuming h_t — keeps 2 loads outstanding.
        v2f hn = 0.0f;
        if (t + 2 < T_STEPS) {
            hn = __builtin_nontemporal_load(ip + (long)(t + 2) * bn2);
        }

        v2f o;
        o.x = mem.x > 1.0f ? 1.0f : 0.0f;
        o.y = mem.y > 1.0f ? 1.0f : 0.0f;

        __builtin_nontemporal_store(o, op + (long)t * bn2);

        // detach_reset: zero where spiked, else leaky integrate with delayed syn.
        mem.x = (o.x != 0.0f) ? 0.0f : fmaf(0.5f, mem.x, syn.x);
        mem.y = (o.y != 0.0f) ? 0.0f : fmaf(0.5f, mem.y, syn.y);

        syn = hA;   // syn_{t+1} = in[t]
        hA = hB;
        hB = hn;
    }
}

extern "C" void kernel_launch(void* const* d_in, const int* in_sizes, int n_in,
                              void* d_out, int out_size, void* d_ws, size_t ws_size,
                              hipStream_t stream) {
    const float* in = (const float*)d_in[0];
    float* out = (float*)d_out;

    const int total = in_sizes[0];          // T * B * N
    const int bn = total / T_STEPS;         // B * N = 524288
    const int bn2 = bn / 2;                 // float2 columns per timestep = 262144

    const int block = 256;
    const int grid = (bn2 + block - 1) / block;  // 1024 blocks

    lif_kernel<<<grid, block, 0, stream>>>((const v2f*)in, (v2f*)out, bn2);
}